// Round 10
// baseline (70.361 us; speedup 1.0000x reference)
//
#include <hip/hip_runtime.h>
#include <math.h>

#define NN 8192
#define JT 256                         // j-tile width = block size
#define IC 64                          // i-chunk per block
#define NJT (NN / JT)                  // 32 j-tiles
#define NBLOCKS (2 * NJT * (NJT + 1))  // 2112 blocks
#define ALPHA_C 3.0f
#define MIN_DIFF_C 0.1f
#define LOG2E 1.44269504088896340736f
#define LN2   0.69314718055994530942f

// R9: LDS-pipe cut. R8 audit: 4 waves/block each re-read all 64 i's ->
// 1056 ds_read_b128/CU ~= 5.3 us LDS occupancy (binding pipe). Now wave w
// owns i-quarter [16w,16w+16) x ALL 256 j (4 j's per lane in registers:
// j0+lane+{0,64,128,192}) -> 4x fewer LDS reads, same VALU totals.
// Inner math unchanged (XOR sign, exp2/log2, ballot count on SALU).
// -log_sigmoid(x)=ln2*log2(1+2^(-x*log2e)); ln2 folded into finalize.
// j-constants are explicit scalars (R2 lesson: indexed arrays -> scratch).

#define PAIR1(PI, TI, TJ, NL, VEX)                                         \
    {                                                                      \
        const float dt  = (TI) - (TJ);                                     \
        const float dps = fmaf((PI), LOG2E, (NL));                         \
        const float xs  = __uint_as_float(__float_as_uint(dps) ^           \
                          (__float_as_uint(dt) & 0x80000000u));            \
        const float e   = __builtin_amdgcn_exp2f(-xs);                     \
        const float lg  = __builtin_amdgcn_logf(1.0f + e);                 \
        const bool valid = (VEX) && (fabsf(dt) > MIN_DIFF_C);              \
        s = fmaf(valid ? fabsf(dt) : 0.0f, lg, s);                         \
        cnt += (unsigned int)__popcll(__ballot(valid));                    \
    }

// one i-value against this lane's 4 j's (full tile: no i<j predicate)
#define I_BODY_FULL(PI, TI)                                                \
    PAIR1(PI, TI, tj0, nl0, true)                                          \
    PAIR1(PI, TI, tj1, nl1, true)                                          \
    PAIR1(PI, TI, tj2, nl2, true)                                          \
    PAIR1(PI, TI, tj3, nl3, true)

// diagonal tile: predicate i < j  (jb = j0+lane; j's are jb, jb+64, ...)
#define I_BODY_DIAG(PI, TI, IDX)                                           \
    PAIR1(PI, TI, tj0, nl0, (IDX) < jb)                                    \
    PAIR1(PI, TI, tj1, nl1, (IDX) < jb + 64)                               \
    PAIR1(PI, TI, tj2, nl2, (IDX) < jb + 128)                              \
    PAIR1(PI, TI, tj3, nl3, (IDX) < jb + 192)

__global__ __launch_bounds__(256, 8) void pair_kernel(
    const float* __restrict__ pred, const float* __restrict__ targ,
    float4* __restrict__ parts) {
    const int b = blockIdx.x;
    // decode b -> (t, ic): blocks before j-tile t = 2*t*(t+1)
    int t = (int)((sqrt(1.0 + 2.0 * (double)b) - 1.0) * 0.5);
    while (2 * (t + 1) * (t + 2) <= b) ++t;
    while (2 * t * (t + 1) > b) --t;
    const int ic = b - 2 * t * (t + 1);
    const int j0 = t * JT;
    const int i0 = ic * IC;
    const int tid  = threadIdx.x;
    const int lane = tid & 63;
    const int w    = tid >> 6;
    const int jb   = j0 + lane;

    // prologue: this lane's 4 j's (coalesced per 64-lane round) + i-stage
    const float pj0 = pred[jb];        const float tj0 = targ[jb];
    const float pj1 = pred[jb + 64];   const float tj1 = targ[jb + 64];
    const float pj2 = pred[jb + 128];  const float tj2 = targ[jb + 128];
    const float pj3 = pred[jb + 192];  const float tj3 = targ[jb + 192];
    __shared__ __align__(16) float sP[IC];
    __shared__ __align__(16) float sT[IC];
    if (tid < IC) { sP[tid] = pred[i0 + tid]; sT[tid] = targ[i0 + tid]; }
    __syncthreads();

    const float nl0 = -pj0 * LOG2E;
    const float nl1 = -pj1 * LOG2E;
    const float nl2 = -pj2 * LOG2E;
    const float nl3 = -pj3 * LOG2E;

    float s = 0.0f;        // sum conf * log2(1+2^-y)   (ln2 applied later)
    float r = 0.0f;        // regression partial
    unsigned int cnt = 0;  // this wave's masked-pair count (wave-uniform)

    const bool diag  = (ic >= 4 * t);
    const int  ibase = i0 + 16 * w;    // this wave's i-range: 16 values

    if (!diag) {
        #pragma unroll
        for (int g = 0; g < 4; ++g) {
            const float4 p4 = *(const float4*)&sP[16 * w + 4 * g]; // ds_read_b128
            const float4 t4 = *(const float4*)&sT[16 * w + 4 * g]; // ds_read_b128
            I_BODY_FULL(p4.x, t4.x)
            I_BODY_FULL(p4.y, t4.y)
            I_BODY_FULL(p4.z, t4.z)
            I_BODY_FULL(p4.w, t4.w)
        }
    } else {
        #pragma unroll
        for (int g = 0; g < 4; ++g) {
            const float4 p4 = *(const float4*)&sP[16 * w + 4 * g];
            const float4 t4 = *(const float4*)&sT[16 * w + 4 * g];
            const int ig = ibase + 4 * g;
            I_BODY_DIAG(p4.x, t4.x, ig + 0)
            I_BODY_DIAG(p4.y, t4.y, ig + 1)
            I_BODY_DIAG(p4.z, t4.z, ig + 2)
            I_BODY_DIAG(p4.w, t4.w, ig + 3)
        }
        // owner block: wave 0's 4 j's/lane cover all 256 j exactly once
        if (ic == 4 * t + 3 && w == 0) {
            const float d0 = pj0 - tj0, d1 = pj1 - tj1;
            const float d2 = pj2 - tj2, d3 = pj3 - tj3;
            r = d0 * d0 + d1 * d1 + d2 * d2 + d3 * d3;
        }
    }

    // ---- block reduction: shuffle s (and r only on diag blocks) ----
    #pragma unroll
    for (int off = 32; off > 0; off >>= 1) s += __shfl_down(s, off, 64);
    if (diag) {
        #pragma unroll
        for (int off = 32; off > 0; off >>= 1) r += __shfl_down(r, off, 64);
    }
    __shared__ float red_s[4], red_c[4], red_r[4];
    if (lane == 0) { red_s[w] = s; red_c[w] = (float)cnt; red_r[w] = r; }
    __syncthreads();
    if (tid == 0) {
        parts[b] = make_float4(red_s[0] + red_s[1] + red_s[2] + red_s[3],
                               red_c[0] + red_c[1] + red_c[2] + red_c[3],
                               red_r[0] + red_r[1] + red_r[2] + red_r[3], 0.0f);
    }
}

__global__ __launch_bounds__(256) void finalize_kernel(
    const float4* __restrict__ parts, float* __restrict__ out) {
    float s = 0.0f, c = 0.0f, r = 0.0f;
    for (int i = threadIdx.x; i < NBLOCKS; i += 256) {
        const float4 v = parts[i];
        s += v.x; c += v.y; r += v.z;
    }
    #pragma unroll
    for (int off = 32; off > 0; off >>= 1) {
        s += __shfl_down(s, off, 64);
        c += __shfl_down(c, off, 64);
        r += __shfl_down(r, off, 64);
    }
    __shared__ float red_s[4], red_c[4], red_r[4];
    const int wave = threadIdx.x >> 6;
    const int lane = threadIdx.x & 63;
    if (lane == 0) { red_s[wave] = s; red_c[wave] = c; red_r[wave] = r; }
    __syncthreads();
    if (threadIdx.x == 0) {
        const float fs = red_s[0] + red_s[1] + red_s[2] + red_s[3];
        const float fc = red_c[0] + red_c[1] + red_c[2] + red_c[3];
        const float fr = red_r[0] + red_r[1] + red_r[2] + red_r[3];
        const float reg = fr / (float)NN;
        const float pm  = LN2 * fs / fmaxf(fc, 1.0f);
        out[0] = (fc > 0.0f) ? (reg + ALPHA_C * pm) : reg;
    }
}

extern "C" void kernel_launch(void* const* d_in, const int* in_sizes, int n_in,
                              void* d_out, int out_size, void* d_ws, size_t ws_size,
                              hipStream_t stream) {
    const float* pred = (const float*)d_in[0];
    const float* targ = (const float*)d_in[1];
    float* out = (float*)d_out;
    float4* parts = (float4*)d_ws;   // NBLOCKS * 16 B = 33,792 B

    pair_kernel<<<NBLOCKS, 256, 0, stream>>>(pred, targ, parts);
    finalize_kernel<<<1, 256, 0, stream>>>(parts, out);
}